// Round 1
// baseline (1232.703 us; speedup 1.0000x reference)
//
#include <hip/hip_runtime.h>
#include <math.h>

#define DIM 64

// ---------------- kernels ----------------

__global__ void deg_kernel(const int* __restrict__ dst, float* __restrict__ deg, int E) {
    int e = blockIdx.x * blockDim.x + threadIdx.x;
    if (e < E) atomicAdd(&deg[dst[e]], 1.0f);
}

__global__ void dis_kernel(float* __restrict__ deg, int n) {
    int i = blockIdx.x * blockDim.x + threadIdx.x;
    if (i < n) {
        float d = deg[i];
        deg[i] = d > 0.0f ? 1.0f / sqrtf(d) : 0.0f;
    }
}

__global__ void w_kernel(const int* __restrict__ src, const int* __restrict__ dst,
                         const float* __restrict__ dis, float* __restrict__ w, int E) {
    int e = blockIdx.x * blockDim.x + threadIdx.x;
    if (e < E) w[e] = dis[src[e]] * dis[dst[e]];
}

__device__ __forceinline__ float softmax_weight(const float* __restrict__ alpha, int li) {
    float a0 = alpha[0], a1 = alpha[1], a2 = alpha[2], a3 = alpha[3];
    float m = fmaxf(fmaxf(a0, a1), fmaxf(a2, a3));
    float e0 = expf(a0 - m), e1 = expf(a1 - m), e2 = expf(a2 - m), e3 = expf(a3 - m);
    float s = e0 + e1 + e2 + e3;
    float sel = (li == 0) ? e0 : (li == 1) ? e1 : (li == 2) ? e2 : e3;
    return sel / s;
}

// out = w0 * emb ; x = emb   (float4 over N*D/4 elements)
__global__ void init_kernel(const float* __restrict__ emb, float* __restrict__ x,
                            float* __restrict__ out, const float* __restrict__ alpha, int n4) {
    int i = blockIdx.x * blockDim.x + threadIdx.x;
    if (i >= n4) return;
    float w0 = softmax_weight(alpha, 0);
    float4 v = ((const float4*)emb)[i];
    ((float4*)x)[i] = v;
    float4 o;
    o.x = v.x * w0; o.y = v.y * w0; o.z = v.z * w0; o.w = v.w * w0;
    ((float4*)out)[i] = o;
}

// y[dst*64+d] += w[e] * x[src*64+d] ; one wave (64 lanes) per edge
__global__ void scatter_kernel(const int* __restrict__ src, const int* __restrict__ dst,
                               const float* __restrict__ w, const float* __restrict__ x,
                               float* __restrict__ y, int E) {
    long long g = (long long)blockIdx.x * blockDim.x + threadIdx.x;
    int e = (int)(g >> 6);
    int d = (int)(g & 63);
    if (e >= E) return;
    int s = src[e];
    int t = dst[e];
    float val = w[e] * x[s * DIM + d];
    atomicAdd(&y[t * DIM + d], val);
}

// out += weights[li] * y   (float4)
__global__ void axpy_kernel(float* __restrict__ out, const float* __restrict__ y,
                            const float* __restrict__ alpha, int li, int n4) {
    int i = blockIdx.x * blockDim.x + threadIdx.x;
    if (i >= n4) return;
    float wl = softmax_weight(alpha, li);
    float4 o = ((float4*)out)[i];
    float4 v = ((const float4*)y)[i];
    o.x += wl * v.x; o.y += wl * v.y; o.z += wl * v.z; o.w += wl * v.w;
    ((float4*)out)[i] = o;
}

// res[e] = dot(out[a[e]], out[b[e]]) ; one wave per edge, shuffle reduce
__global__ void dot_kernel(const int* __restrict__ a, const int* __restrict__ b,
                           const float* __restrict__ out, float* __restrict__ res, int E) {
    long long g = (long long)blockIdx.x * blockDim.x + threadIdx.x;
    int e = (int)(g >> 6);
    int d = (int)(g & 63);
    if (e >= E) return;
    int ia = a[e];
    int ib = b[e];
    float v = out[ia * DIM + d] * out[ib * DIM + d];
    #pragma unroll
    for (int off = 32; off > 0; off >>= 1)
        v += __shfl_xor(v, off, 64);
    if (d == 0) res[e] = v;
}

// ---------------- launcher ----------------

static inline size_t align256(size_t x) { return (x + 255) & ~(size_t)255; }

extern "C" void kernel_launch(void* const* d_in, const int* in_sizes, int n_in,
                              void* d_out, int out_size, void* d_ws, size_t ws_size,
                              hipStream_t stream) {
    const int* edge_index = (const int*)d_in[0];       // [2, E]
    const int* edge_label = (const int*)d_in[1];       // [2, E]
    const float* emb      = (const float*)d_in[2];     // [N, D]
    const float* alpha    = (const float*)d_in[3];     // [L+1]

    const int E = in_sizes[0] / 2;
    const int N = in_sizes[2] / DIM;

    const int* src = edge_index;
    const int* dst = edge_index + E;
    const int* la  = edge_label;
    const int* lb  = edge_label + E;

    // workspace layout
    char* ws = (char*)d_ws;
    size_t off = 0;
    float* deg = (float*)(ws + off); off = align256(off + (size_t)N * 4);
    float* w   = (float*)(ws + off); off = align256(off + (size_t)E * 4);
    float* bufA = (float*)(ws + off); off = align256(off + (size_t)N * DIM * 4);
    float* bufB = (float*)(ws + off); off = align256(off + (size_t)N * DIM * 4);
    float* out  = (float*)(ws + off); off = align256(off + (size_t)N * DIM * 4);
    (void)ws_size;

    const int B = 256;
    const int gridE  = (E + B - 1) / B;
    const int gridN  = (N + B - 1) / B;
    const int n4     = N * DIM / 4;
    const int grid4  = (n4 + B - 1) / B;
    const long long tot = (long long)E * DIM;
    const int gridED = (int)((tot + B - 1) / B);

    // degree -> dis
    hipMemsetAsync(deg, 0, (size_t)N * 4, stream);
    deg_kernel<<<gridE, B, 0, stream>>>(dst, deg, E);
    dis_kernel<<<gridN, B, 0, stream>>>(deg, N);
    w_kernel<<<gridE, B, 0, stream>>>(src, dst, deg, w, E);

    // init: x = emb, out = w0*emb
    init_kernel<<<grid4, B, 0, stream>>>(emb, bufA, out, alpha, n4);

    float* x = bufA;
    float* y = bufB;
    for (int li = 1; li <= 3; ++li) {
        hipMemsetAsync(y, 0, (size_t)N * DIM * 4, stream);
        scatter_kernel<<<gridED, B, 0, stream>>>(src, dst, w, x, y, E);
        axpy_kernel<<<grid4, B, 0, stream>>>(out, y, alpha, li, n4);
        float* t = x; x = y; y = t;
    }

    // per-edge dot products
    dot_kernel<<<gridED, B, 0, stream>>>(la, lb, out, (float*)d_out, E);
}

// Round 2
// 543.822 us; speedup vs baseline: 2.2667x; 2.2667x over previous
//
#include <hip/hip_runtime.h>
#include <math.h>

#define DIM 64
#define SCAN_CHUNK 1024

// ---------------- degree / normalization ----------------

__global__ void hist_kernel(const int* __restrict__ dst, int* __restrict__ cnt, int E) {
    int e = blockIdx.x * blockDim.x + threadIdx.x;
    if (e < E) atomicAdd(&cnt[dst[e]], 1);
}

__global__ void dis_kernel(const int* __restrict__ cnt, float* __restrict__ dis, int n) {
    int i = blockIdx.x * blockDim.x + threadIdx.x;
    if (i < n) {
        int d = cnt[i];
        dis[i] = d > 0 ? 1.0f / sqrtf((float)d) : 0.0f;
    }
}

// ---------------- prefix sum (3-phase block scan) ----------------

// phase 1: per-block (1024-elem chunk) sums
__global__ void scan1_kernel(const int* __restrict__ cnt, int* __restrict__ bsum, int N) {
    __shared__ int s[256];
    int t = threadIdx.x;
    int base = blockIdx.x * SCAN_CHUNK + t * 4;
    int sum = 0;
    #pragma unroll
    for (int k = 0; k < 4; ++k) {
        int i = base + k;
        if (i < N) sum += cnt[i];
    }
    s[t] = sum; __syncthreads();
    for (int off = 128; off > 0; off >>= 1) {
        if (t < off) s[t] += s[t + off];
        __syncthreads();
    }
    if (t == 0) bsum[blockIdx.x] = s[0];
}

// phase 2: exclusive scan of block sums (nb <= 256), also writes rowptr[N]=E
__global__ void scan2_kernel(int* __restrict__ bsum, int* __restrict__ rowptr,
                             int nb, int N, int E) {
    __shared__ int s[256];
    int t = threadIdx.x;
    int v = (t < nb) ? bsum[t] : 0;
    s[t] = v; __syncthreads();
    #pragma unroll
    for (int off = 1; off < 256; off <<= 1) {
        int add = (t >= off) ? s[t - off] : 0;
        __syncthreads();
        s[t] += add;
        __syncthreads();
    }
    if (t < nb) bsum[t] = s[t] - v;   // exclusive
    if (t == 0) rowptr[N] = E;
}

// phase 3: per-chunk exclusive scan + block offset -> rowptr
__global__ void scan3_kernel(const int* __restrict__ cnt, const int* __restrict__ bsum,
                             int* __restrict__ rowptr, int N) {
    __shared__ int s[256];
    int t = threadIdx.x;
    int base = blockIdx.x * SCAN_CHUNK + t * 4;
    int v[4]; int sum = 0;
    #pragma unroll
    for (int k = 0; k < 4; ++k) {
        int i = base + k;
        v[k] = (i < N) ? cnt[i] : 0;
        sum += v[k];
    }
    s[t] = sum; __syncthreads();
    #pragma unroll
    for (int off = 1; off < 256; off <<= 1) {
        int add = (t >= off) ? s[t - off] : 0;
        __syncthreads();
        s[t] += add;
        __syncthreads();
    }
    int excl = s[t] - sum + bsum[blockIdx.x];
    #pragma unroll
    for (int k = 0; k < 4; ++k) {
        int i = base + k;
        if (i < N) rowptr[i] = excl;
        excl += v[k];
    }
}

__global__ void copy_kernel(const int* __restrict__ a, int* __restrict__ b, int n) {
    int i = blockIdx.x * blockDim.x + threadIdx.x;
    if (i < n) b[i] = a[i];
}

// scatter edges into CSR slots; fuse per-edge weight computation
__global__ void fill_kernel(const int* __restrict__ src, const int* __restrict__ dst,
                            const float* __restrict__ dis, int* __restrict__ pos,
                            int* __restrict__ csr_src, float* __restrict__ csr_w, int E) {
    int e = blockIdx.x * blockDim.x + threadIdx.x;
    if (e >= E) return;
    int s = src[e], t = dst[e];
    int p = atomicAdd(&pos[t], 1);
    csr_src[p] = s;
    csr_w[p]   = dis[s] * dis[t];
}

// ---------------- layer compute ----------------

__device__ __forceinline__ float softmax_weight(const float* __restrict__ alpha, int li) {
    float a0 = alpha[0], a1 = alpha[1], a2 = alpha[2], a3 = alpha[3];
    float m = fmaxf(fmaxf(a0, a1), fmaxf(a2, a3));
    float e0 = expf(a0 - m), e1 = expf(a1 - m), e2 = expf(a2 - m), e3 = expf(a3 - m);
    float s = e0 + e1 + e2 + e3;
    float sel = (li == 0) ? e0 : (li == 1) ? e1 : (li == 2) ? e2 : e3;
    return sel / s;
}

// out = w0 * emb (float4)
__global__ void init_kernel(const float* __restrict__ emb, float* __restrict__ out,
                            const float* __restrict__ alpha, int n4) {
    int i = blockIdx.x * blockDim.x + threadIdx.x;
    if (i >= n4) return;
    float w0 = softmax_weight(alpha, 0);
    float4 v = ((const float4*)emb)[i];
    float4 o;
    o.x = v.x * w0; o.y = v.y * w0; o.z = v.z * w0; o.w = v.w * w0;
    ((float4*)out)[i] = o;
}

// fused SpMM (gather, no atomics) + out += wl * y
// one wave per node, lane = feature dim
__global__ void spmm_kernel(const int* __restrict__ rowptr, const int* __restrict__ csr_src,
                            const float* __restrict__ csr_w, const float* __restrict__ x,
                            float* __restrict__ y, float* __restrict__ out,
                            const float* __restrict__ alpha, int li, int N) {
    int wave = (int)(((long long)blockIdx.x * blockDim.x + threadIdx.x) >> 6);
    int d = threadIdx.x & 63;
    if (wave >= N) return;
    int v = wave;
    int beg = rowptr[v], end = rowptr[v + 1];
    float acc = 0.0f;
    int j = beg;
    for (; j + 1 < end; j += 2) {
        int   s0 = csr_src[j],  s1 = csr_src[j + 1];
        float w0 = csr_w[j],    w1 = csr_w[j + 1];
        acc += w0 * x[s0 * DIM + d];
        acc += w1 * x[s1 * DIM + d];
    }
    if (j < end) acc += csr_w[j] * x[csr_src[j] * DIM + d];
    y[v * DIM + d] = acc;
    float wl = softmax_weight(alpha, li);
    out[v * DIM + d] += wl * acc;
}

// res[e] = dot(out[a[e]], out[b[e]]) ; 16 lanes per edge, float4 loads
__global__ void dot_kernel(const int* __restrict__ a, const int* __restrict__ b,
                           const float* __restrict__ out, float* __restrict__ res, int E) {
    long long g = (long long)blockIdx.x * blockDim.x + threadIdx.x;
    int e   = (int)(g >> 4);
    int sub = (int)(g & 15);
    if (e >= E) return;
    int ia = a[e];
    int ib = b[e];
    float4 va = ((const float4*)out)[ia * 16 + sub];
    float4 vb = ((const float4*)out)[ib * 16 + sub];
    float v = va.x * vb.x + va.y * vb.y + va.z * vb.z + va.w * vb.w;
    #pragma unroll
    for (int off = 8; off > 0; off >>= 1)
        v += __shfl_xor(v, off, 64);
    if (sub == 0) res[e] = v;
}

// ---------------- launcher ----------------

static inline size_t align256(size_t x) { return (x + 255) & ~(size_t)255; }

extern "C" void kernel_launch(void* const* d_in, const int* in_sizes, int n_in,
                              void* d_out, int out_size, void* d_ws, size_t ws_size,
                              hipStream_t stream) {
    const int* edge_index = (const int*)d_in[0];       // [2, E]
    const int* edge_label = (const int*)d_in[1];       // [2, E]
    const float* emb      = (const float*)d_in[2];     // [N, D]
    const float* alpha    = (const float*)d_in[3];     // [L+1]

    const int E = in_sizes[0] / 2;
    const int N = in_sizes[2] / DIM;

    const int* src = edge_index;
    const int* dst = edge_index + E;
    const int* la  = edge_label;
    const int* lb  = edge_label + E;

    // workspace layout (~88 MB)
    char* ws = (char*)d_ws;
    size_t off = 0;
    int*   cnt     = (int*)(ws + off);   off = align256(off + (size_t)N * 4);
    float* dis     = (float*)(ws + off); off = align256(off + (size_t)N * 4);
    int*   rowptr  = (int*)(ws + off);   off = align256(off + (size_t)(N + 1) * 4);
    int*   pos     = (int*)(ws + off);   off = align256(off + (size_t)N * 4);
    int*   bsum    = (int*)(ws + off);   off = align256(off + (size_t)256 * 4);
    int*   csr_src = (int*)(ws + off);   off = align256(off + (size_t)E * 4);
    float* csr_w   = (float*)(ws + off); off = align256(off + (size_t)E * 4);
    float* bufA    = (float*)(ws + off); off = align256(off + (size_t)N * DIM * 4);
    float* bufB    = (float*)(ws + off); off = align256(off + (size_t)N * DIM * 4);
    float* outbuf  = (float*)(ws + off); off = align256(off + (size_t)N * DIM * 4);
    (void)ws_size;

    const int B = 256;
    const int gridE = (E + B - 1) / B;
    const int gridN = (N + B - 1) / B;
    const int nb    = (N + SCAN_CHUNK - 1) / SCAN_CHUNK;   // <= 256 for N <= 256K
    const int n4    = N * DIM / 4;
    const int grid4 = (n4 + B - 1) / B;

    // 1. degree histogram + symmetric norm
    hipMemsetAsync(cnt, 0, (size_t)N * 4, stream);
    hist_kernel<<<gridE, B, 0, stream>>>(dst, cnt, E);
    dis_kernel<<<gridN, B, 0, stream>>>(cnt, dis, N);

    // 2. CSR build: prefix sum + fill
    scan1_kernel<<<nb, B, 0, stream>>>(cnt, bsum, N);
    scan2_kernel<<<1, B, 0, stream>>>(bsum, rowptr, nb, N, E);
    scan3_kernel<<<nb, B, 0, stream>>>(cnt, bsum, rowptr, N);
    copy_kernel<<<gridN, B, 0, stream>>>(rowptr, pos, N);
    fill_kernel<<<gridE, B, 0, stream>>>(src, dst, dis, pos, csr_src, csr_w, E);

    // 3. out = w0 * emb
    init_kernel<<<grid4, B, 0, stream>>>(emb, outbuf, alpha, n4);

    // 4. three fused gather-SpMM + axpy layers (no atomics)
    const long long nthreads = (long long)N * DIM;
    const int gridND = (int)((nthreads + B - 1) / B);
    spmm_kernel<<<gridND, B, 0, stream>>>(rowptr, csr_src, csr_w, emb,  bufA, outbuf, alpha, 1, N);
    spmm_kernel<<<gridND, B, 0, stream>>>(rowptr, csr_src, csr_w, bufA, bufB, outbuf, alpha, 2, N);
    spmm_kernel<<<gridND, B, 0, stream>>>(rowptr, csr_src, csr_w, bufB, bufA, outbuf, alpha, 3, N);

    // 5. per-edge dot products
    const long long dthreads = (long long)E * 16;
    const int gridD = (int)((dthreads + B - 1) / B);
    dot_kernel<<<gridD, B, 0, stream>>>(la, lb, outbuf, (float*)d_out, E);
}

// Round 3
// 471.653 us; speedup vs baseline: 2.6136x; 1.1530x over previous
//
#include <hip/hip_runtime.h>
#include <math.h>

#define DIM 64
#define SCAN_CHUNK 1024

// ---------------- degree / normalization ----------------

__global__ void hist_kernel(const int* __restrict__ dst, int* __restrict__ cnt, int E) {
    int e = blockIdx.x * blockDim.x + threadIdx.x;
    if (e < E) atomicAdd(&cnt[dst[e]], 1);
}

__global__ void dis_kernel(const int* __restrict__ cnt, float* __restrict__ dis, int n) {
    int i = blockIdx.x * blockDim.x + threadIdx.x;
    if (i < n) {
        int d = cnt[i];
        dis[i] = d > 0 ? 1.0f / sqrtf((float)d) : 0.0f;
    }
}

// ---------------- prefix sum (3-phase block scan) ----------------

__global__ void scan1_kernel(const int* __restrict__ cnt, int* __restrict__ bsum, int N) {
    __shared__ int s[256];
    int t = threadIdx.x;
    int base = blockIdx.x * SCAN_CHUNK + t * 4;
    int sum = 0;
    #pragma unroll
    for (int k = 0; k < 4; ++k) {
        int i = base + k;
        if (i < N) sum += cnt[i];
    }
    s[t] = sum; __syncthreads();
    for (int off = 128; off > 0; off >>= 1) {
        if (t < off) s[t] += s[t + off];
        __syncthreads();
    }
    if (t == 0) bsum[blockIdx.x] = s[0];
}

__global__ void scan2_kernel(int* __restrict__ bsum, int* __restrict__ rowptr,
                             int nb, int N, int E) {
    __shared__ int s[256];
    int t = threadIdx.x;
    int v = (t < nb) ? bsum[t] : 0;
    s[t] = v; __syncthreads();
    #pragma unroll
    for (int off = 1; off < 256; off <<= 1) {
        int add = (t >= off) ? s[t - off] : 0;
        __syncthreads();
        s[t] += add;
        __syncthreads();
    }
    if (t < nb) bsum[t] = s[t] - v;   // exclusive
    if (t == 0) rowptr[N] = E;
}

__global__ void scan3_kernel(const int* __restrict__ cnt, const int* __restrict__ bsum,
                             int* __restrict__ rowptr, int N) {
    __shared__ int s[256];
    int t = threadIdx.x;
    int base = blockIdx.x * SCAN_CHUNK + t * 4;
    int v[4]; int sum = 0;
    #pragma unroll
    for (int k = 0; k < 4; ++k) {
        int i = base + k;
        v[k] = (i < N) ? cnt[i] : 0;
        sum += v[k];
    }
    s[t] = sum; __syncthreads();
    #pragma unroll
    for (int off = 1; off < 256; off <<= 1) {
        int add = (t >= off) ? s[t - off] : 0;
        __syncthreads();
        s[t] += add;
        __syncthreads();
    }
    int excl = s[t] - sum + bsum[blockIdx.x];
    #pragma unroll
    for (int k = 0; k < 4; ++k) {
        int i = base + k;
        if (i < N) rowptr[i] = excl;
        excl += v[k];
    }
}

__global__ void copy_kernel(const int* __restrict__ a, int* __restrict__ b, int n) {
    int i = blockIdx.x * blockDim.x + threadIdx.x;
    if (i < n) b[i] = a[i];
}

// scatter edges into CSR slots; single 8B record per edge {src, w}
__global__ void fill_kernel(const int* __restrict__ src, const int* __restrict__ dst,
                            const float* __restrict__ dis, int* __restrict__ pos,
                            int2* __restrict__ csr, int E) {
    int e = blockIdx.x * blockDim.x + threadIdx.x;
    if (e >= E) return;
    int s = src[e], t = dst[e];
    int p = atomicAdd(&pos[t], 1);
    int2 rec;
    rec.x = s;
    rec.y = __float_as_int(dis[s] * dis[t]);
    csr[p] = rec;
}

// ---------------- layer compute ----------------

__device__ __forceinline__ float softmax_weight(const float* __restrict__ alpha, int li) {
    float a0 = alpha[0], a1 = alpha[1], a2 = alpha[2], a3 = alpha[3];
    float m = fmaxf(fmaxf(a0, a1), fmaxf(a2, a3));
    float e0 = expf(a0 - m), e1 = expf(a1 - m), e2 = expf(a2 - m), e3 = expf(a3 - m);
    float s = e0 + e1 + e2 + e3;
    float sel = (li == 0) ? e0 : (li == 1) ? e1 : (li == 2) ? e2 : e3;
    return sel / s;
}

// out = w0 * emb (float4)
__global__ void init_kernel(const float* __restrict__ emb, float* __restrict__ out,
                            const float* __restrict__ alpha, int n4) {
    int i = blockIdx.x * blockDim.x + threadIdx.x;
    if (i >= n4) return;
    float w0 = softmax_weight(alpha, 0);
    float4 v = ((const float4*)emb)[i];
    float4 o;
    o.x = v.x * w0; o.y = v.y * w0; o.z = v.z * w0; o.w = v.w * w0;
    ((float4*)out)[i] = o;
}

// fused SpMM (gather) + out += wl * y
// one wave per node; lane = eslot*16 + sub; 4 edge-slots x 16 lanes x float4
__global__ void spmm_kernel(const int* __restrict__ rowptr, const int2* __restrict__ csr,
                            const float* __restrict__ x, float* __restrict__ y,
                            float* __restrict__ out, const float* __restrict__ alpha,
                            int li, int N) {
    int lane = threadIdx.x & 63;
    int v = blockIdx.x * (blockDim.x >> 6) + (threadIdx.x >> 6);
    if (v >= N) return;
    int eslot = lane >> 4;
    int sub   = lane & 15;
    int beg = rowptr[v], end = rowptr[v + 1];
    float4 acc = make_float4(0.f, 0.f, 0.f, 0.f);
    for (int j = beg + eslot; j < end; j += 4) {
        int2 m = csr[j];
        float w = __int_as_float(m.y);
        float4 xv = ((const float4*)x)[m.x * 16 + sub];
        acc.x += w * xv.x; acc.y += w * xv.y;
        acc.z += w * xv.z; acc.w += w * xv.w;
    }
    // reduce across the 4 edge-slots
    #pragma unroll
    for (int off = 16; off <= 32; off <<= 1) {
        acc.x += __shfl_xor(acc.x, off, 64);
        acc.y += __shfl_xor(acc.y, off, 64);
        acc.z += __shfl_xor(acc.z, off, 64);
        acc.w += __shfl_xor(acc.w, off, 64);
    }
    if (eslot == 0) {
        ((float4*)y)[v * 16 + sub] = acc;
        float wl = softmax_weight(alpha, li);
        float4 o = ((float4*)out)[v * 16 + sub];
        o.x += wl * acc.x; o.y += wl * acc.y;
        o.z += wl * acc.z; o.w += wl * acc.w;
        ((float4*)out)[v * 16 + sub] = o;
    }
}

// res[e] = dot(out[a[e]], out[b[e]]) ; 16 lanes per edge, float4 loads
__global__ void dot_kernel(const int* __restrict__ a, const int* __restrict__ b,
                           const float* __restrict__ out, float* __restrict__ res, int E) {
    long long g = (long long)blockIdx.x * blockDim.x + threadIdx.x;
    int e   = (int)(g >> 4);
    int sub = (int)(g & 15);
    if (e >= E) return;
    int ia = a[e];
    int ib = b[e];
    float4 va = ((const float4*)out)[ia * 16 + sub];
    float4 vb = ((const float4*)out)[ib * 16 + sub];
    float v = va.x * vb.x + va.y * vb.y + va.z * vb.z + va.w * vb.w;
    #pragma unroll
    for (int off = 8; off > 0; off >>= 1)
        v += __shfl_xor(v, off, 64);
    if (sub == 0) res[e] = v;
}

// ---------------- launcher ----------------

static inline size_t align256(size_t x) { return (x + 255) & ~(size_t)255; }

extern "C" void kernel_launch(void* const* d_in, const int* in_sizes, int n_in,
                              void* d_out, int out_size, void* d_ws, size_t ws_size,
                              hipStream_t stream) {
    const int* edge_index = (const int*)d_in[0];       // [2, E]
    const int* edge_label = (const int*)d_in[1];       // [2, E]
    const float* emb      = (const float*)d_in[2];     // [N, D]
    const float* alpha    = (const float*)d_in[3];     // [L+1]

    const int E = in_sizes[0] / 2;
    const int N = in_sizes[2] / DIM;

    const int* src = edge_index;
    const int* dst = edge_index + E;
    const int* la  = edge_label;
    const int* lb  = edge_label + E;

    // workspace layout (~88 MB)
    char* ws = (char*)d_ws;
    size_t off = 0;
    int*   cnt     = (int*)(ws + off);   off = align256(off + (size_t)N * 4);
    float* dis     = (float*)(ws + off); off = align256(off + (size_t)N * 4);
    int*   rowptr  = (int*)(ws + off);   off = align256(off + (size_t)(N + 1) * 4);
    int*   pos     = (int*)(ws + off);   off = align256(off + (size_t)N * 4);
    int*   bsum    = (int*)(ws + off);   off = align256(off + (size_t)256 * 4);
    int2*  csr     = (int2*)(ws + off);  off = align256(off + (size_t)E * 8);
    float* bufA    = (float*)(ws + off); off = align256(off + (size_t)N * DIM * 4);
    float* bufB    = (float*)(ws + off); off = align256(off + (size_t)N * DIM * 4);
    float* outbuf  = (float*)(ws + off); off = align256(off + (size_t)N * DIM * 4);
    (void)ws_size;

    const int B = 256;
    const int gridE = (E + B - 1) / B;
    const int gridN = (N + B - 1) / B;
    const int nb    = (N + SCAN_CHUNK - 1) / SCAN_CHUNK;   // <= 256 for N <= 256K
    const int n4    = N * DIM / 4;
    const int grid4 = (n4 + B - 1) / B;

    // 1. degree histogram + symmetric norm
    hipMemsetAsync(cnt, 0, (size_t)N * 4, stream);
    hist_kernel<<<gridE, B, 0, stream>>>(dst, cnt, E);
    dis_kernel<<<gridN, B, 0, stream>>>(cnt, dis, N);

    // 2. CSR build: prefix sum + fill
    scan1_kernel<<<nb, B, 0, stream>>>(cnt, bsum, N);
    scan2_kernel<<<1, B, 0, stream>>>(bsum, rowptr, nb, N, E);
    scan3_kernel<<<nb, B, 0, stream>>>(cnt, bsum, rowptr, N);
    copy_kernel<<<gridN, B, 0, stream>>>(rowptr, pos, N);
    fill_kernel<<<gridE, B, 0, stream>>>(src, dst, dis, pos, csr, E);

    // 3. out = w0 * emb
    init_kernel<<<grid4, B, 0, stream>>>(emb, outbuf, alpha, n4);

    // 4. three fused gather-SpMM + axpy layers (no atomics)
    const int wavesPerBlock = B / 64;
    const int gridS = (N + wavesPerBlock - 1) / wavesPerBlock;
    spmm_kernel<<<gridS, B, 0, stream>>>(rowptr, csr, emb,  bufA, outbuf, alpha, 1, N);
    spmm_kernel<<<gridS, B, 0, stream>>>(rowptr, csr, bufA, bufB, outbuf, alpha, 2, N);
    spmm_kernel<<<gridS, B, 0, stream>>>(rowptr, csr, bufB, bufA, outbuf, alpha, 3, N);

    // 5. per-edge dot products
    const long long dthreads = (long long)E * 16;
    const int gridD = (int)((dthreads + B - 1) / B);
    dot_kernel<<<gridD, B, 0, stream>>>(la, lb, outbuf, (float*)d_out, E);
}

// Round 4
// 442.387 us; speedup vs baseline: 2.7865x; 1.0662x over previous
//
#include <hip/hip_runtime.h>
#include <math.h>

#define DIM 64
#define SCAN_CHUNK 1024

// ---------------- degree / normalization ----------------

__global__ void hist_kernel(const int* __restrict__ dst, int* __restrict__ cnt, int E) {
    int e = blockIdx.x * blockDim.x + threadIdx.x;
    if (e < E) atomicAdd(&cnt[dst[e]], 1);
}

__global__ void dis_kernel(const int* __restrict__ cnt, float* __restrict__ dis, int n) {
    int i = blockIdx.x * blockDim.x + threadIdx.x;
    if (i < n) {
        int d = cnt[i];
        dis[i] = d > 0 ? 1.0f / sqrtf((float)d) : 0.0f;
    }
}

// ---------------- prefix sum (3-phase block scan) ----------------

__global__ void scan1_kernel(const int* __restrict__ cnt, int* __restrict__ bsum, int N) {
    __shared__ int s[256];
    int t = threadIdx.x;
    int base = blockIdx.x * SCAN_CHUNK + t * 4;
    int sum = 0;
    #pragma unroll
    for (int k = 0; k < 4; ++k) {
        int i = base + k;
        if (i < N) sum += cnt[i];
    }
    s[t] = sum; __syncthreads();
    for (int off = 128; off > 0; off >>= 1) {
        if (t < off) s[t] += s[t + off];
        __syncthreads();
    }
    if (t == 0) bsum[blockIdx.x] = s[0];
}

__global__ void scan2_kernel(int* __restrict__ bsum, int* __restrict__ rowptr,
                             int nb, int N, int E) {
    __shared__ int s[256];
    int t = threadIdx.x;
    int v = (t < nb) ? bsum[t] : 0;
    s[t] = v; __syncthreads();
    #pragma unroll
    for (int off = 1; off < 256; off <<= 1) {
        int add = (t >= off) ? s[t - off] : 0;
        __syncthreads();
        s[t] += add;
        __syncthreads();
    }
    if (t < nb) bsum[t] = s[t] - v;   // exclusive
    if (t == 0) rowptr[N] = E;
}

// phase 3: per-chunk exclusive scan + block offset -> rowptr AND pos (fused copy)
__global__ void scan3_kernel(const int* __restrict__ cnt, const int* __restrict__ bsum,
                             int* __restrict__ rowptr, int* __restrict__ pos, int N) {
    __shared__ int s[256];
    int t = threadIdx.x;
    int base = blockIdx.x * SCAN_CHUNK + t * 4;
    int v[4]; int sum = 0;
    #pragma unroll
    for (int k = 0; k < 4; ++k) {
        int i = base + k;
        v[k] = (i < N) ? cnt[i] : 0;
        sum += v[k];
    }
    s[t] = sum; __syncthreads();
    #pragma unroll
    for (int off = 1; off < 256; off <<= 1) {
        int add = (t >= off) ? s[t - off] : 0;
        __syncthreads();
        s[t] += add;
        __syncthreads();
    }
    int excl = s[t] - sum + bsum[blockIdx.x];
    #pragma unroll
    for (int k = 0; k < 4; ++k) {
        int i = base + k;
        if (i < N) { rowptr[i] = excl; pos[i] = excl; }
        excl += v[k];
    }
}

// scatter edges into CSR slots; single 8B record per edge {src, w}
__global__ void fill_kernel(const int* __restrict__ src, const int* __restrict__ dst,
                            const float* __restrict__ dis, int* __restrict__ pos,
                            int2* __restrict__ csr, int E) {
    int e = blockIdx.x * blockDim.x + threadIdx.x;
    if (e >= E) return;
    int s = src[e], t = dst[e];
    int p = atomicAdd(&pos[t], 1);
    int2 rec;
    rec.x = s;
    rec.y = __float_as_int(dis[s] * dis[t]);
    csr[p] = rec;
}

// ---------------- layer compute ----------------

__device__ __forceinline__ void softmax4(const float* __restrict__ alpha, float* w) {
    float a0 = alpha[0], a1 = alpha[1], a2 = alpha[2], a3 = alpha[3];
    float m = fmaxf(fmaxf(a0, a1), fmaxf(a2, a3));
    float e0 = expf(a0 - m), e1 = expf(a1 - m), e2 = expf(a2 - m), e3 = expf(a3 - m);
    float s = 1.0f / (e0 + e1 + e2 + e3);
    w[0] = e0 * s; w[1] = e1 * s; w[2] = e2 * s; w[3] = e3 * s;
}

// SpMM (gather, no atomics): y = A_hat * x
// one wave per node; lane = eslot*16 + sub; 4 edge-slots x 16 lanes x float4
__global__ void spmm_kernel(const int* __restrict__ rowptr, const int2* __restrict__ csr,
                            const float* __restrict__ x, float* __restrict__ y, int N) {
    int lane = threadIdx.x & 63;
    int v = blockIdx.x * (blockDim.x >> 6) + (threadIdx.x >> 6);
    if (v >= N) return;
    int eslot = lane >> 4;
    int sub   = lane & 15;
    int beg = rowptr[v], end = rowptr[v + 1];
    float4 acc = make_float4(0.f, 0.f, 0.f, 0.f);
    for (int j = beg + eslot; j < end; j += 4) {
        int2 m = csr[j];
        float w = __int_as_float(m.y);
        float4 xv = ((const float4*)x)[m.x * 16 + sub];
        acc.x += w * xv.x; acc.y += w * xv.y;
        acc.z += w * xv.z; acc.w += w * xv.w;
    }
    #pragma unroll
    for (int off = 16; off <= 32; off <<= 1) {
        acc.x += __shfl_xor(acc.x, off, 64);
        acc.y += __shfl_xor(acc.y, off, 64);
        acc.z += __shfl_xor(acc.z, off, 64);
        acc.w += __shfl_xor(acc.w, off, 64);
    }
    if (eslot == 0) {
        ((float4*)y)[v * 16 + sub] = acc;
    }
}

// last layer: x3 = A_hat * x2 computed in-register; fused final combine:
// out = w0*emb + w1*x1 + w2*x2 + w3*x3   (all coalesced reads; x3 never stored)
__global__ void spmm_final_kernel(const int* __restrict__ rowptr, const int2* __restrict__ csr,
                                  const float* __restrict__ emb, const float* __restrict__ x1,
                                  const float* __restrict__ x2, float* __restrict__ out,
                                  const float* __restrict__ alpha, int N) {
    int lane = threadIdx.x & 63;
    int v = blockIdx.x * (blockDim.x >> 6) + (threadIdx.x >> 6);
    if (v >= N) return;
    int eslot = lane >> 4;
    int sub   = lane & 15;
    int beg = rowptr[v], end = rowptr[v + 1];
    float4 acc = make_float4(0.f, 0.f, 0.f, 0.f);
    for (int j = beg + eslot; j < end; j += 4) {
        int2 m = csr[j];
        float w = __int_as_float(m.y);
        float4 xv = ((const float4*)x2)[m.x * 16 + sub];
        acc.x += w * xv.x; acc.y += w * xv.y;
        acc.z += w * xv.z; acc.w += w * xv.w;
    }
    #pragma unroll
    for (int off = 16; off <= 32; off <<= 1) {
        acc.x += __shfl_xor(acc.x, off, 64);
        acc.y += __shfl_xor(acc.y, off, 64);
        acc.z += __shfl_xor(acc.z, off, 64);
        acc.w += __shfl_xor(acc.w, off, 64);
    }
    if (eslot == 0) {
        float w[4];
        softmax4(alpha, w);
        float4 e0 = ((const float4*)emb)[v * 16 + sub];
        float4 v1 = ((const float4*)x1)[v * 16 + sub];
        float4 v2 = ((const float4*)x2)[v * 16 + sub];
        float4 o;
        o.x = w[0] * e0.x + w[1] * v1.x + w[2] * v2.x + w[3] * acc.x;
        o.y = w[0] * e0.y + w[1] * v1.y + w[2] * v2.y + w[3] * acc.y;
        o.z = w[0] * e0.z + w[1] * v1.z + w[2] * v2.z + w[3] * acc.z;
        o.w = w[0] * e0.w + w[1] * v1.w + w[2] * v2.w + w[3] * acc.w;
        ((float4*)out)[v * 16 + sub] = o;
    }
}

// res[e] = dot(out[a[e]], out[b[e]]) ; 16 lanes per edge, float4 loads
__global__ void dot_kernel(const int* __restrict__ a, const int* __restrict__ b,
                           const float* __restrict__ out, float* __restrict__ res, int E) {
    long long g = (long long)blockIdx.x * blockDim.x + threadIdx.x;
    int e   = (int)(g >> 4);
    int sub = (int)(g & 15);
    if (e >= E) return;
    int ia = a[e];
    int ib = b[e];
    float4 va = ((const float4*)out)[ia * 16 + sub];
    float4 vb = ((const float4*)out)[ib * 16 + sub];
    float v = va.x * vb.x + va.y * vb.y + va.z * vb.z + va.w * vb.w;
    #pragma unroll
    for (int off = 8; off > 0; off >>= 1)
        v += __shfl_xor(v, off, 64);
    if (sub == 0) res[e] = v;
}

// ---------------- launcher ----------------

static inline size_t align256(size_t x) { return (x + 255) & ~(size_t)255; }

extern "C" void kernel_launch(void* const* d_in, const int* in_sizes, int n_in,
                              void* d_out, int out_size, void* d_ws, size_t ws_size,
                              hipStream_t stream) {
    const int* edge_index = (const int*)d_in[0];       // [2, E]
    const int* edge_label = (const int*)d_in[1];       // [2, E]
    const float* emb      = (const float*)d_in[2];     // [N, D]
    const float* alpha    = (const float*)d_in[3];     // [L+1]

    const int E = in_sizes[0] / 2;
    const int N = in_sizes[2] / DIM;

    const int* src = edge_index;
    const int* dst = edge_index + E;
    const int* la  = edge_label;
    const int* lb  = edge_label + E;

    // workspace layout (~90 MB)
    char* ws = (char*)d_ws;
    size_t off = 0;
    int*   cnt     = (int*)(ws + off);   off = align256(off + (size_t)N * 4);
    float* dis     = (float*)(ws + off); off = align256(off + (size_t)N * 4);
    int*   rowptr  = (int*)(ws + off);   off = align256(off + (size_t)(N + 1) * 4);
    int*   pos     = (int*)(ws + off);   off = align256(off + (size_t)N * 4);
    int*   bsum    = (int*)(ws + off);   off = align256(off + (size_t)256 * 4);
    int2*  csr     = (int2*)(ws + off);  off = align256(off + (size_t)E * 8);
    float* x1      = (float*)(ws + off); off = align256(off + (size_t)N * DIM * 4);
    float* x2      = (float*)(ws + off); off = align256(off + (size_t)N * DIM * 4);
    float* outbuf  = (float*)(ws + off); off = align256(off + (size_t)N * DIM * 4);
    (void)ws_size;

    const int B = 256;
    const int gridE = (E + B - 1) / B;
    const int gridN = (N + B - 1) / B;
    const int nb    = (N + SCAN_CHUNK - 1) / SCAN_CHUNK;   // <= 256 for N <= 256K

    // 1. degree histogram + symmetric norm
    hipMemsetAsync(cnt, 0, (size_t)N * 4, stream);
    hist_kernel<<<gridE, B, 0, stream>>>(dst, cnt, E);
    dis_kernel<<<gridN, B, 0, stream>>>(cnt, dis, N);

    // 2. CSR build: prefix sum (pos fused into scan3) + fill
    scan1_kernel<<<nb, B, 0, stream>>>(cnt, bsum, N);
    scan2_kernel<<<1, B, 0, stream>>>(bsum, rowptr, nb, N, E);
    scan3_kernel<<<nb, B, 0, stream>>>(cnt, bsum, rowptr, pos, N);
    fill_kernel<<<gridE, B, 0, stream>>>(src, dst, dis, pos, csr, E);

    // 3. three gather-SpMM layers; out-combine fused into the last
    const int wavesPerBlock = B / 64;
    const int gridS = (N + wavesPerBlock - 1) / wavesPerBlock;
    spmm_kernel<<<gridS, B, 0, stream>>>(rowptr, csr, emb, x1, N);
    spmm_kernel<<<gridS, B, 0, stream>>>(rowptr, csr, x1, x2, N);
    spmm_final_kernel<<<gridS, B, 0, stream>>>(rowptr, csr, emb, x1, x2, outbuf, alpha, N);

    // 4. per-edge dot products
    const long long dthreads = (long long)E * 16;
    const int gridD = (int)((dthreads + B - 1) / B);
    dot_kernel<<<gridD, B, 0, stream>>>(la, lb, outbuf, (float*)d_out, E);
}

// Round 5
// 365.355 us; speedup vs baseline: 3.3740x; 1.2108x over previous
//
#include <hip/hip_runtime.h>
#include <math.h>

#define DIM 64
#define SCAN_CHUNK 1024

typedef _Float16 half8 __attribute__((ext_vector_type(8)));

// ---------------- degree / normalization ----------------

__global__ void hist_kernel(const int* __restrict__ dst, int* __restrict__ cnt, int E) {
    int e = blockIdx.x * blockDim.x + threadIdx.x;
    if (e < E) atomicAdd(&cnt[dst[e]], 1);
}

__global__ void dis_kernel(const int* __restrict__ cnt, float* __restrict__ dis, int n) {
    int i = blockIdx.x * blockDim.x + threadIdx.x;
    if (i < n) {
        int d = cnt[i];
        dis[i] = d > 0 ? 1.0f / sqrtf((float)d) : 0.0f;
    }
}

// ---------------- prefix sum (3-phase block scan) ----------------

__global__ void scan1_kernel(const int* __restrict__ cnt, int* __restrict__ bsum, int N) {
    __shared__ int s[256];
    int t = threadIdx.x;
    int base = blockIdx.x * SCAN_CHUNK + t * 4;
    int sum = 0;
    #pragma unroll
    for (int k = 0; k < 4; ++k) {
        int i = base + k;
        if (i < N) sum += cnt[i];
    }
    s[t] = sum; __syncthreads();
    for (int off = 128; off > 0; off >>= 1) {
        if (t < off) s[t] += s[t + off];
        __syncthreads();
    }
    if (t == 0) bsum[blockIdx.x] = s[0];
}

__global__ void scan2_kernel(int* __restrict__ bsum, int* __restrict__ rowptr,
                             int nb, int N, int E) {
    __shared__ int s[256];
    int t = threadIdx.x;
    int v = (t < nb) ? bsum[t] : 0;
    s[t] = v; __syncthreads();
    #pragma unroll
    for (int off = 1; off < 256; off <<= 1) {
        int add = (t >= off) ? s[t - off] : 0;
        __syncthreads();
        s[t] += add;
        __syncthreads();
    }
    if (t < nb) bsum[t] = s[t] - v;   // exclusive
    if (t == 0) rowptr[N] = E;
}

// phase 3: per-chunk exclusive scan + block offset -> rowptr AND pos
__global__ void scan3_kernel(const int* __restrict__ cnt, const int* __restrict__ bsum,
                             int* __restrict__ rowptr, int* __restrict__ pos, int N) {
    __shared__ int s[256];
    int t = threadIdx.x;
    int base = blockIdx.x * SCAN_CHUNK + t * 4;
    int v[4]; int sum = 0;
    #pragma unroll
    for (int k = 0; k < 4; ++k) {
        int i = base + k;
        v[k] = (i < N) ? cnt[i] : 0;
        sum += v[k];
    }
    s[t] = sum; __syncthreads();
    #pragma unroll
    for (int off = 1; off < 256; off <<= 1) {
        int add = (t >= off) ? s[t - off] : 0;
        __syncthreads();
        s[t] += add;
        __syncthreads();
    }
    int excl = s[t] - sum + bsum[blockIdx.x];
    #pragma unroll
    for (int k = 0; k < 4; ++k) {
        int i = base + k;
        if (i < N) { rowptr[i] = excl; pos[i] = excl; }
        excl += v[k];
    }
}

// scatter edges into CSR slots; single 8B record per edge {src, w}
__global__ void fill_kernel(const int* __restrict__ src, const int* __restrict__ dst,
                            const float* __restrict__ dis, int* __restrict__ pos,
                            int2* __restrict__ csr, int E) {
    int e = blockIdx.x * blockDim.x + threadIdx.x;
    if (e >= E) return;
    int s = src[e], t = dst[e];
    int p = atomicAdd(&pos[t], 1);
    int2 rec;
    rec.x = s;
    rec.y = __float_as_int(dis[s] * dis[t]);
    csr[p] = rec;
}

// ---------------- fp16 conversion of emb ----------------

__global__ void conv_kernel(const float* __restrict__ emb, half8* __restrict__ embh, int n8) {
    int i = blockIdx.x * blockDim.x + threadIdx.x;
    if (i >= n8) return;
    const float4* e4 = (const float4*)emb;
    float4 a = e4[2 * i], b = e4[2 * i + 1];
    half8 h;
    h[0] = (_Float16)a.x; h[1] = (_Float16)a.y; h[2] = (_Float16)a.z; h[3] = (_Float16)a.w;
    h[4] = (_Float16)b.x; h[5] = (_Float16)b.y; h[6] = (_Float16)b.z; h[7] = (_Float16)b.w;
    embh[i] = h;
}

// ---------------- layer compute ----------------

__device__ __forceinline__ void softmax4(const float* __restrict__ alpha, float* w) {
    float a0 = alpha[0], a1 = alpha[1], a2 = alpha[2], a3 = alpha[3];
    float m = fmaxf(fmaxf(a0, a1), fmaxf(a2, a3));
    float e0 = expf(a0 - m), e1 = expf(a1 - m), e2 = expf(a2 - m), e3 = expf(a3 - m);
    float s = 1.0f / (e0 + e1 + e2 + e3);
    w[0] = e0 * s; w[1] = e1 * s; w[2] = e2 * s; w[3] = e3 * s;
}

// SpMM (gather): y = A_hat * x ; fp16 rows (128 B)
// one wave per node; lane = slot*8 + sub; 8 edge-slots x 8 lanes x half8(16B)
__global__ void spmm_kernel(const int* __restrict__ rowptr, const int2* __restrict__ csr,
                            const half8* __restrict__ x, half8* __restrict__ y, int N) {
    int lane = threadIdx.x & 63;
    int v = blockIdx.x * (blockDim.x >> 6) + (threadIdx.x >> 6);
    if (v >= N) return;
    int slot = lane >> 3;
    int sub  = lane & 7;
    int beg = rowptr[v], end = rowptr[v + 1];
    float acc[8] = {0.f, 0.f, 0.f, 0.f, 0.f, 0.f, 0.f, 0.f};
    for (int j = beg + slot; j < end; j += 8) {
        int2 m = csr[j];
        float w = __int_as_float(m.y);
        half8 xv = x[m.x * 8 + sub];
        #pragma unroll
        for (int k = 0; k < 8; ++k) acc[k] += w * (float)xv[k];
    }
    #pragma unroll
    for (int off = 8; off <= 32; off <<= 1) {
        #pragma unroll
        for (int k = 0; k < 8; ++k) acc[k] += __shfl_xor(acc[k], off, 64);
    }
    if (slot == 0) {
        half8 o;
        #pragma unroll
        for (int k = 0; k < 8; ++k) o[k] = (_Float16)acc[k];
        y[v * 8 + sub] = o;
    }
}

// last layer: x3 = A_hat * x2 in-register; fused combine:
// out = w0*emb(fp32) + w1*x1 + w2*x2 + w3*x3 ; out stored fp16
__global__ void spmm_final_kernel(const int* __restrict__ rowptr, const int2* __restrict__ csr,
                                  const float* __restrict__ emb, const half8* __restrict__ x1,
                                  const half8* __restrict__ x2, half8* __restrict__ out,
                                  const float* __restrict__ alpha, int N) {
    int lane = threadIdx.x & 63;
    int v = blockIdx.x * (blockDim.x >> 6) + (threadIdx.x >> 6);
    if (v >= N) return;
    int slot = lane >> 3;
    int sub  = lane & 7;
    int beg = rowptr[v], end = rowptr[v + 1];
    float acc[8] = {0.f, 0.f, 0.f, 0.f, 0.f, 0.f, 0.f, 0.f};
    for (int j = beg + slot; j < end; j += 8) {
        int2 m = csr[j];
        float w = __int_as_float(m.y);
        half8 xv = x2[m.x * 8 + sub];
        #pragma unroll
        for (int k = 0; k < 8; ++k) acc[k] += w * (float)xv[k];
    }
    #pragma unroll
    for (int off = 8; off <= 32; off <<= 1) {
        #pragma unroll
        for (int k = 0; k < 8; ++k) acc[k] += __shfl_xor(acc[k], off, 64);
    }
    if (slot == 0) {
        float w[4];
        softmax4(alpha, w);
        const float4* e4 = (const float4*)emb;
        float4 ea = e4[v * 16 + sub * 2];
        float4 eb = e4[v * 16 + sub * 2 + 1];
        half8 h1 = x1[v * 8 + sub];
        half8 h2 = x2[v * 8 + sub];
        float ef[8] = {ea.x, ea.y, ea.z, ea.w, eb.x, eb.y, eb.z, eb.w};
        half8 o;
        #pragma unroll
        for (int k = 0; k < 8; ++k) {
            float val = w[0] * ef[k] + w[1] * (float)h1[k] + w[2] * (float)h2[k] + w[3] * acc[k];
            o[k] = (_Float16)val;
        }
        out[v * 8 + sub] = o;
    }
}

// res[e] = dot(out[a[e]], out[b[e]]) ; 8 lanes per edge, half8 (16B) loads
__global__ void dot_kernel(const int* __restrict__ a, const int* __restrict__ b,
                           const half8* __restrict__ out, float* __restrict__ res, int E) {
    long long g = (long long)blockIdx.x * blockDim.x + threadIdx.x;
    int e   = (int)(g >> 3);
    int sub = (int)(g & 7);
    if (e >= E) return;
    int ia = a[e];
    int ib = b[e];
    half8 va = out[ia * 8 + sub];
    half8 vb = out[ib * 8 + sub];
    float v = 0.f;
    #pragma unroll
    for (int k = 0; k < 8; ++k) v += (float)va[k] * (float)vb[k];
    #pragma unroll
    for (int off = 1; off <= 4; off <<= 1)
        v += __shfl_xor(v, off, 64);
    if (sub == 0) res[e] = v;
}

// ---------------- launcher ----------------

static inline size_t align256(size_t x) { return (x + 255) & ~(size_t)255; }

extern "C" void kernel_launch(void* const* d_in, const int* in_sizes, int n_in,
                              void* d_out, int out_size, void* d_ws, size_t ws_size,
                              hipStream_t stream) {
    const int* edge_index = (const int*)d_in[0];       // [2, E]
    const int* edge_label = (const int*)d_in[1];       // [2, E]
    const float* emb      = (const float*)d_in[2];     // [N, D]
    const float* alpha    = (const float*)d_in[3];     // [L+1]

    const int E = in_sizes[0] / 2;
    const int N = in_sizes[2] / DIM;

    const int* src = edge_index;
    const int* dst = edge_index + E;
    const int* la  = edge_label;
    const int* lb  = edge_label + E;

    // workspace layout (~65 MB)
    char* ws = (char*)d_ws;
    size_t off = 0;
    int*   cnt     = (int*)(ws + off);   off = align256(off + (size_t)N * 4);
    float* dis     = (float*)(ws + off); off = align256(off + (size_t)N * 4);
    int*   rowptr  = (int*)(ws + off);   off = align256(off + (size_t)(N + 1) * 4);
    int*   pos     = (int*)(ws + off);   off = align256(off + (size_t)N * 4);
    int*   bsum    = (int*)(ws + off);   off = align256(off + (size_t)256 * 4);
    int2*  csr     = (int2*)(ws + off);  off = align256(off + (size_t)E * 8);
    half8* embh    = (half8*)(ws + off); off = align256(off + (size_t)N * DIM * 2);
    half8* x1      = (half8*)(ws + off); off = align256(off + (size_t)N * DIM * 2);
    half8* x2      = (half8*)(ws + off); off = align256(off + (size_t)N * DIM * 2);
    half8* outbuf  = (half8*)(ws + off); off = align256(off + (size_t)N * DIM * 2);
    (void)ws_size;

    const int B = 256;
    const int gridE = (E + B - 1) / B;
    const int gridN = (N + B - 1) / B;
    const int nb    = (N + SCAN_CHUNK - 1) / SCAN_CHUNK;   // <= 256 for N <= 256K

    // 1. degree histogram + symmetric norm (overlaps with conv)
    hipMemsetAsync(cnt, 0, (size_t)N * 4, stream);
    hist_kernel<<<gridE, B, 0, stream>>>(dst, cnt, E);
    dis_kernel<<<gridN, B, 0, stream>>>(cnt, dis, N);

    // 2. fp16 copy of emb
    const int n8 = N * DIM / 8;
    conv_kernel<<<(n8 + B - 1) / B, B, 0, stream>>>(emb, embh, n8);

    // 3. CSR build: prefix sum (pos fused into scan3) + fill
    scan1_kernel<<<nb, B, 0, stream>>>(cnt, bsum, N);
    scan2_kernel<<<1, B, 0, stream>>>(bsum, rowptr, nb, N, E);
    scan3_kernel<<<nb, B, 0, stream>>>(cnt, bsum, rowptr, pos, N);
    fill_kernel<<<gridE, B, 0, stream>>>(src, dst, dis, pos, csr, E);

    // 4. three gather-SpMM layers (fp16 rows); combine fused into the last
    const int wavesPerBlock = B / 64;
    const int gridS = (N + wavesPerBlock - 1) / wavesPerBlock;
    spmm_kernel<<<gridS, B, 0, stream>>>(rowptr, csr, embh, x1, N);
    spmm_kernel<<<gridS, B, 0, stream>>>(rowptr, csr, x1, x2, N);
    spmm_final_kernel<<<gridS, B, 0, stream>>>(rowptr, csr, emb, x1, x2, outbuf, alpha, N);

    // 5. per-edge dot products
    const long long dthreads = (long long)E * 8;
    const int gridD = (int)((dthreads + B - 1) / B);
    dot_kernel<<<gridD, B, 0, stream>>>(la, lb, outbuf, (float*)d_out, E);
}